// Round 13
// baseline (124.997 us; speedup 1.0000x reference)
//
#include <hip/hip_runtime.h>
#include <stdint.h>

typedef __bf16 bf16x8 __attribute__((ext_vector_type(8)));
typedef __bf16 bf16x2v __attribute__((ext_vector_type(2)));
typedef float f32x4 __attribute__((ext_vector_type(4)));
typedef uint16_t u16x8 __attribute__((ext_vector_type(8)));
typedef uint32_t u32x2 __attribute__((ext_vector_type(2)));
typedef short s16x4 __attribute__((ext_vector_type(4)));

#define DMODEL 1024
#define K1SC 0.1803368801111244f  /* (1/8) * log2(e) */

__device__ __forceinline__ uint16_t bfc(float f) {
  __bf16 h = (__bf16)f;
  return __builtin_bit_cast(uint16_t, h);
}
__device__ __forceinline__ uint32_t pk32(float a, float b) {
  bf16x2v t = {(__bf16)a, (__bf16)b};
  return __builtin_bit_cast(uint32_t, t);
}
__device__ __forceinline__ void gld16(const void* src, void* dst) {
  __builtin_amdgcn_global_load_lds((const __attribute__((address_space(1))) void*)src,
                                   (__attribute__((address_space(3))) void*)dst, 16, 0, 0);
}

// ---------------- fused QKV projection: batched GEMM, 128x64, BK=32 ----------
// Smaller tile for TLP: grid 1536 -> 6 blocks/CU capacity (24KB LDS).
// fp32 inputs, cvt fused into reg-staging. Chunk-XOR LDS (writes free,
// reads 4-way). z==0 (Q) pre-scaled by K1SC.
__global__ __launch_bounds__(256, 4)
void gemm_qkv_kernel(const float* __restrict__ A0, const float* __restrict__ A1,
                     const float* __restrict__ A2, const float* __restrict__ W0,
                     const float* __restrict__ W1, const float* __restrict__ W2,
                     uint16_t* __restrict__ C0, uint16_t* __restrict__ C1,
                     uint16_t* __restrict__ C2) {
  int orig = blockIdx.x;                 // 1536 blocks, 192-chunk per XCD
  int lin = (orig & 7) * 192 + (orig >> 3);
  int z = lin >> 9, rem = lin & 511;
  int m0 = (rem >> 4) * 128, n0 = (rem & 15) * 64;

  const float* A  = z == 0 ? A0 : (z == 1 ? A1 : A2);
  const float* Bw = z == 0 ? W0 : (z == 1 ? W1 : W2);
  uint16_t* C = z == 0 ? C0 : (z == 1 ? C1 : C2);
  const float osc = (z == 0) ? K1SC : 1.0f;

  __shared__ __align__(16) char As[2][128 * 64];
  __shared__ __align__(16) char Bs[2][64 * 64];
  const int t = threadIdx.x;
  const int lane = t & 63;
  const int w = t >> 6;
  const int wr = w >> 1, wc = w & 1;
  const int lr = lane & 15, ksl = lane >> 4;

  // A staging: thread -> row t>>1 (128 rows), chunks {(t&1)*2, (t&1)*2+1}
  const int arow = t >> 1, asc = (t & 1) * 2;
  const float* pa = A + (size_t)(m0 + arow) * DMODEL + asc * 8;
  const int sda0 = arow * 64 + ((asc ^ (arow & 3)) * 16);
  const int sda1 = arow * 64 + (((asc + 1) ^ (arow & 3)) * 16);
  // B staging: thread -> row t>>2 (64 rows), chunk t&3
  const int brow = t >> 2, bsc = t & 3;
  const float* pb = Bw + (size_t)(n0 + brow) * DMODEL + bsc * 8;
  const int sdb = brow * 64 + ((bsc ^ (brow & 3)) * 16);

  f32x4 la0, la1, la2, la3, lb0, lb1;
  auto LOAD = [&]() {
    la0 = *(const f32x4*)pa;       la1 = *(const f32x4*)(pa + 4);
    la2 = *(const f32x4*)(pa + 8); la3 = *(const f32x4*)(pa + 12);
    lb0 = *(const f32x4*)pb;       lb1 = *(const f32x4*)(pb + 4);
  };
  auto pack2 = [](f32x4 x, f32x4 y) {
    u16x8 r;
#pragma unroll
    for (int j = 0; j < 4; ++j) { r[j] = bfc(x[j]); r[4 + j] = bfc(y[j]); }
    return r;
  };
  auto STORE = [&](int buf) {
    char* ab = &As[buf][0];
    *(u16x8*)(ab + sda0) = pack2(la0, la1);
    *(u16x8*)(ab + sda1) = pack2(la2, la3);
    *(u16x8*)(&Bs[buf][0] + sdb) = pack2(lb0, lb1);
  };

  f32x4 acc[4][2];
#pragma unroll
  for (int m = 0; m < 4; ++m)
#pragma unroll
    for (int n = 0; n < 2; ++n) acc[m][n] = (f32x4){0.f, 0.f, 0.f, 0.f};

  LOAD();
  STORE(0);
  __syncthreads();

  const int co = (ksl ^ (lr & 3)) * 16;

  int cur = 0;
#pragma unroll 1
  for (int kt = 0; kt < 32; ++kt) {
    if (kt < 31) { pa += 32; pb += 32; LOAD(); }
    const char* Ab = &As[cur][0];
    const char* Bb = &Bs[cur][0];
    bf16x8 af[4], bfv[2];
#pragma unroll
    for (int m = 0; m < 4; ++m)
      af[m] = *(const bf16x8*)(Ab + (wr * 64 + m * 16 + lr) * 64 + co);
#pragma unroll
    for (int n = 0; n < 2; ++n)
      bfv[n] = *(const bf16x8*)(Bb + (wc * 32 + n * 16 + lr) * 64 + co);
    __builtin_amdgcn_s_setprio(1);
#pragma unroll
    for (int m = 0; m < 4; ++m)
#pragma unroll
      for (int n = 0; n < 2; ++n)
        acc[m][n] = __builtin_amdgcn_mfma_f32_16x16x32_bf16(af[m], bfv[n], acc[m][n], 0, 0, 0);
    __builtin_amdgcn_s_setprio(0);
    if (kt < 31) STORE(cur ^ 1);
    __syncthreads();
    cur ^= 1;
  }

#pragma unroll
  for (int m = 0; m < 4; ++m) {
#pragma unroll
    for (int n = 0; n < 2; ++n) {
      int col = n0 + wc * 32 + n * 16 + lr;
#pragma unroll
      for (int r = 0; r < 4; ++r) {
        int row = m0 + wr * 64 + m * 16 + ksl * 4 + r;
        C[(size_t)row * DMODEL + col] = bfc(acc[m][n][r] * osc);
      }
    }
  }
}

// ---------------- output GEMM: C = A*Wo^T + resid, fp32 out, 64x128, BK=32 ---
// A = Cc bf16 (reg-staged), B = Wo fp32 (reg-staged cvt). Chunk-XOR LDS.
__global__ __launch_bounds__(256, 4)
void gemm_o_kernel(const uint16_t* __restrict__ Ac, const float* __restrict__ Bw,
                   float* __restrict__ Cf, const float* __restrict__ resid) {
  int orig = blockIdx.x;                 // 512 blocks, 64-chunk per XCD
  int lin = (orig & 7) * 64 + (orig >> 3);
  int m0 = (lin >> 3) * 64, n0 = (lin & 7) * 128;

  __shared__ __align__(16) char As[2][64 * 64];
  __shared__ __align__(16) char Bs[2][128 * 64];
  const int t = threadIdx.x;
  const int lane = t & 63;
  const int w = t >> 6;
  const int wr = w >> 1, wc = w & 1;
  const int lr = lane & 15, ksl = lane >> 4;

  const int srow = t >> 2, sch = t & 3;
  const uint16_t* pc = Ac + (size_t)(m0 + srow) * DMODEL + sch * 8;  // srow<64
  const float* pb = Bw + (size_t)(n0 + srow) * DMODEL + sch * 8;
  const int sd = srow * 64 + ((sch ^ (srow & 3)) * 16);

  u16x8 lc;
  f32x4 lb0, lb1, lb2, lb3;
  auto LOAD = [&]() {
    lc = *(const u16x8*)pc;
    lb0 = *(const f32x4*)pb;           lb1 = *(const f32x4*)(pb + 4);
    lb2 = *(const f32x4*)(pb + 65536); lb3 = *(const f32x4*)(pb + 65540);
  };
  auto pack2 = [](f32x4 x, f32x4 y) {
    u16x8 r;
#pragma unroll
    for (int j = 0; j < 4; ++j) { r[j] = bfc(x[j]); r[4 + j] = bfc(y[j]); }
    return r;
  };
  auto STORE = [&](int buf) {
    *(u16x8*)(&As[buf][0] + sd) = lc;
    char* bb = &Bs[buf][0];
    *(u16x8*)(bb + sd) = pack2(lb0, lb1);
    *(u16x8*)(bb + sd + 4096) = pack2(lb2, lb3);
  };

  f32x4 acc[2][4];
#pragma unroll
  for (int m = 0; m < 2; ++m)
#pragma unroll
    for (int n = 0; n < 4; ++n) acc[m][n] = (f32x4){0.f, 0.f, 0.f, 0.f};

  LOAD();
  STORE(0);
  __syncthreads();

  const int co = (ksl ^ (lr & 3)) * 16;

  int cur = 0;
#pragma unroll 1
  for (int kt = 0; kt < 32; ++kt) {
    if (kt < 31) { pc += 32; pb += 32; LOAD(); }
    const char* Ab = &As[cur][0];
    const char* Bb = &Bs[cur][0];
    bf16x8 af[2], bfv[4];
#pragma unroll
    for (int m = 0; m < 2; ++m)
      af[m] = *(const bf16x8*)(Ab + (wr * 32 + m * 16 + lr) * 64 + co);
#pragma unroll
    for (int n = 0; n < 4; ++n)
      bfv[n] = *(const bf16x8*)(Bb + (wc * 64 + n * 16 + lr) * 64 + co);
    __builtin_amdgcn_s_setprio(1);
#pragma unroll
    for (int m = 0; m < 2; ++m)
#pragma unroll
      for (int n = 0; n < 4; ++n)
        acc[m][n] = __builtin_amdgcn_mfma_f32_16x16x32_bf16(af[m], bfv[n], acc[m][n], 0, 0, 0);
    __builtin_amdgcn_s_setprio(0);
    if (kt < 31) STORE(cur ^ 1);
    __syncthreads();
    cur ^= 1;
  }

#pragma unroll
  for (int m = 0; m < 2; ++m) {
#pragma unroll
    for (int n = 0; n < 4; ++n) {
      int col = n0 + wc * 64 + n * 16 + lr;
#pragma unroll
      for (int r = 0; r < 4; ++r) {
        int row = m0 + wr * 32 + m * 16 + ksl * 4 + r;
        size_t idx = (size_t)row * DMODEL + col;
        Cf[idx] = acc[m][n][r] + resid[idx];
      }
    }
  }
}

// ---------------- MFMA flash attention (R10-proven, unchanged) ---------------
__global__ __launch_bounds__(256, 4)
void attn_mfma_kernel(const uint16_t* __restrict__ Pq, const uint16_t* __restrict__ Pk,
                      const uint16_t* __restrict__ Pv, uint16_t* __restrict__ Cc) {
  __shared__ __align__(16) uint16_t Ks[2][64 * 64];
  __shared__ __align__(16) uint16_t Vts[2][64 * 64];

  const int t = threadIdx.x;
  const int w = t >> 6;
  const int lane = t & 63;
  const int lr = lane & 15;
  const int ksl = lane >> 4;
  int orig = blockIdx.x;
  int lin = (orig & 7) * 128 + (orig >> 3);
  const int bh = lin >> 4, qt = lin & 15;
  const int b = bh >> 4, h = bh & 15;

  const uint16_t* Qb = Pq + (size_t)bh * 65536 + (size_t)qt * 4096;
  const uint16_t* Kb = Pk + (size_t)bh * 65536;
  const uint16_t* Vb = Pv + (size_t)bh * 65536;

  bf16x8 qf0, qf1;
  {
    const uint16_t* qrow = Qb + (size_t)(w * 16 + lr) * 64 + ksl * 8;
    qf0 = *(const bf16x8*)(qrow);
    qf1 = *(const bf16x8*)(qrow + 32);
  }

  f32x4 Oa[4];
#pragma unroll
  for (int n = 0; n < 4; ++n) Oa[n] = (f32x4){0.f, 0.f, 0.f, 0.f};
  f32x4 lsum4 = {0.f, 0.f, 0.f, 0.f};

  const int sw = (lr & 7) << 4;
  const int p2 = t & 31;
  const int c8 = t >> 5;

  int qko[4][2], pvo[4][4], wvo[8];
#pragma unroll
  for (int n = 0; n < 4; ++n) {
#pragma unroll
    for (int c = 0; c < 2; ++c) qko[n][c] = (n * 16 + lr) * 128 + ((c * 64 + ksl * 16) ^ sw);
#pragma unroll
    for (int nd = 0; nd < 4; ++nd) pvo[n][nd] = (nd * 16 + lr) * 128 + ((n * 32 + ksl * 8) ^ sw);
  }
#pragma unroll
  for (int i = 0; i < 8; ++i) {
    int d = c8 * 8 + i;
    wvo[i] = d * 128 + ((p2 * 4) ^ ((d & 7) << 4));
  }

  const int sr0 = t >> 3;
  const int sc0 = (((t & 7) * 16) ^ ((sr0 & 7) << 4)) >> 1;
  const uint16_t* srcK = Kb + (size_t)sr0 * 64 + sc0;
  const uint16_t* srcV = Vb + (size_t)(p2 * 2) * 64 + c8 * 8;
  const int kd0 = t * 16, kd1 = (256 + t) * 16;

  char* kb0 = (char*)&Ks[0][0];
  char* kb1 = (char*)&Ks[1][0];
  char* vb0 = (char*)&Vts[0][0];
  char* vb1 = (char*)&Vts[1][0];

  u16x8 va, vb2;
  auto stageK = [&](char* kbuf) {
    gld16(srcK, kbuf + kd0);
    gld16(srcK + 2048, kbuf + kd1);
  };
  auto loadV = [&]() {
    va = *(const u16x8*)srcV;
    vb2 = *(const u16x8*)(srcV + 64);
  };
  auto writeV = [&](char* vbuf) {
#pragma unroll
    for (int i = 0; i < 8; ++i) {
      uint32_t val = (uint32_t)va[i] | ((uint32_t)vb2[i] << 16);
      *(uint32_t*)(vbuf + wvo[i]) = val;
    }
  };

  stageK(kb0);
  loadV();
  writeV(vb0);
  __syncthreads();

  const char* kcur = kb0; char* knx = kb1;
  const char* vcur = vb0; char* vnx = vb1;

#pragma unroll 1
  for (int kt = 0; kt < 16; ++kt) {
    if (kt < 15) { srcK += 4096; stageK(knx); srcV += 4096; loadV(); }

    f32x4 S[4];
#pragma unroll
    for (int n = 0; n < 4; ++n) S[n] = (f32x4){0.f, 0.f, 0.f, 0.f};
    __builtin_amdgcn_s_setprio(1);
#pragma unroll
    for (int n = 0; n < 4; ++n) {
      bf16x8 kf0 = *(const bf16x8*)(kcur + qko[n][0]);
      bf16x8 kf1 = *(const bf16x8*)(kcur + qko[n][1]);
      S[n] = __builtin_amdgcn_mfma_f32_16x16x32_bf16(kf0, qf0, S[n], 0, 0, 0);
      S[n] = __builtin_amdgcn_mfma_f32_16x16x32_bf16(kf1, qf1, S[n], 0, 0, 0);
    }
    __builtin_amdgcn_s_setprio(0);

    f32x4 psum = {0.f, 0.f, 0.f, 0.f};
    f32x4 p4[4];
#pragma unroll
    for (int n = 0; n < 4; ++n) {
#pragma unroll
      for (int r = 0; r < 4; ++r) {
        float x = S[n][r];
        float e = __builtin_amdgcn_exp2f(x);
        p4[n][r] = (x == 0.f) ? 0.f : e;
      }
      psum += p4[n];
    }
    lsum4 += psum;

    __builtin_amdgcn_s_setprio(1);
#pragma unroll
    for (int n = 0; n < 4; ++n) {
      u32x2 pa32 = {pk32(p4[n][0], p4[n][1]), pk32(p4[n][2], p4[n][3])};
      s16x4 pa = __builtin_bit_cast(s16x4, pa32);
#pragma unroll
      for (int nd = 0; nd < 4; ++nd) {
        s16x4 vf = *(const s16x4*)(vcur + pvo[n][nd]);
        Oa[nd] = __builtin_amdgcn_mfma_f32_16x16x16bf16_1k(pa, vf, Oa[nd], 0, 0, 0);
      }
    }
    __builtin_amdgcn_s_setprio(0);

    if (kt < 15) writeV(vnx);
    __syncthreads();
    const char* tk = kcur; kcur = knx; knx = (char*)tk;
    const char* tv = vcur; vcur = vnx; vnx = (char*)tv;
  }

  float lrow = (lsum4[0] + lsum4[1]) + (lsum4[2] + lsum4[3]);
  lrow += __shfl_xor(lrow, 16);
  lrow += __shfl_xor(lrow, 32);
  f32x4 inv4;
#pragma unroll
  for (int r = 0; r < 4; ++r) inv4[r] = 1.f / __shfl(lrow, ksl * 4 + r);

  uint16_t* dst = Cc + (size_t)b * 1048576 + (size_t)(qt * 64 + w * 16) * 1024 + h * 64;
#pragma unroll
  for (int r = 0; r < 4; ++r) {
    int qq = ksl * 4 + r;
#pragma unroll
    for (int n = 0; n < 4; ++n) {
      dst[qq * 1024 + n * 16 + lr] = bfc(Oa[n][r] * inv4[r]);
    }
  }
}

// ---------------- host-side orchestration ------------------------------------
extern "C" void kernel_launch(void* const* d_in, const int* in_sizes, int n_in,
                              void* d_out, int out_size, void* d_ws, size_t ws_size,
                              hipStream_t stream) {
  const float* q  = (const float*)d_in[0];
  const float* k  = (const float*)d_in[1];
  const float* v  = (const float*)d_in[2];
  const float* Wq = (const float*)d_in[3];
  const float* Wk = (const float*)d_in[4];
  const float* Wv = (const float*)d_in[5];
  const float* Wo = (const float*)d_in[6];
  float* out = (float*)d_out;
  char* ws = (char*)d_ws;
  const size_t MB = 1u << 20;
  uint16_t* Pq = (uint16_t*)(ws + 0 * MB);
  uint16_t* Pk = (uint16_t*)(ws + 8 * MB);
  uint16_t* Pv = (uint16_t*)(ws + 16 * MB);
  uint16_t* Cc = (uint16_t*)(ws + 24 * MB);

  gemm_qkv_kernel<<<1536, 256, 0, stream>>>(q, k, v, Wq, Wk, Wv, Pq, Pk, Pv);

  attn_mfma_kernel<<<1024, 256, 0, stream>>>(Pq, Pk, Pv, Cc);

  gemm_o_kernel<<<512, 256, 0, stream>>>(Cc, Wo, out, q);
}

// Round 14
// 102.978 us; speedup vs baseline: 1.2138x; 1.2138x over previous
//
#include <hip/hip_runtime.h>
#include <stdint.h>

typedef __bf16 bf16x8 __attribute__((ext_vector_type(8)));
typedef __bf16 bf16x2v __attribute__((ext_vector_type(2)));
typedef float f32x4 __attribute__((ext_vector_type(4)));
typedef uint16_t u16x8 __attribute__((ext_vector_type(8)));
typedef uint32_t u32x2 __attribute__((ext_vector_type(2)));
typedef short s16x4 __attribute__((ext_vector_type(4)));

#define DMODEL 1024
#define K1SC 0.1803368801111244f  /* (1/8) * log2(e) */

__device__ __forceinline__ uint16_t bfc(float f) {
  __bf16 h = (__bf16)f;
  return __builtin_bit_cast(uint16_t, h);
}
__device__ __forceinline__ uint32_t pk32(float a, float b) {
  bf16x2v t = {(__bf16)a, (__bf16)b};
  return __builtin_bit_cast(uint32_t, t);
}
__device__ __forceinline__ void gld16(const void* src, void* dst) {
  __builtin_amdgcn_global_load_lds((const __attribute__((address_space(1))) void*)src,
                                   (__attribute__((address_space(3))) void*)dst, 16, 0, 0);
}

// ---------------- fused QKV projection: batched GEMM, 128x128, BK=32 ---------
// fp32 inputs, cvt fused into reg-staging. Chunk-XOR LDS (writes free, reads
// 4-way). NEW: 2-deep register load pipeline — tile i+3 issued while tile i
// computes; the vmcnt wait at STORE(i+1) is for loads issued 2 iters ago,
// hiding ~700cyc HBM latency behind a full iteration (grid-limited to 3
// blocks/CU, so latency must be hidden by ILP not TLP).
__global__ __launch_bounds__(256, 2)
void gemm_qkv_kernel(const float* __restrict__ A0, const float* __restrict__ A1,
                     const float* __restrict__ A2, const float* __restrict__ W0,
                     const float* __restrict__ W1, const float* __restrict__ W2,
                     uint16_t* __restrict__ C0, uint16_t* __restrict__ C1,
                     uint16_t* __restrict__ C2) {
  int orig = blockIdx.x;                 // 768 blocks, 96-chunk per XCD
  int lin = (orig & 7) * 96 + (orig >> 3);
  int z = lin >> 8, rem = lin & 255;
  int m0 = (rem >> 3) * 128, n0 = (rem & 7) * 128;

  const float* A  = z == 0 ? A0 : (z == 1 ? A1 : A2);
  const float* Bw = z == 0 ? W0 : (z == 1 ? W1 : W2);
  uint16_t* C = z == 0 ? C0 : (z == 1 ? C1 : C2);
  const float osc = (z == 0) ? K1SC : 1.0f;

  __shared__ __align__(16) char As[2][128 * 64];
  __shared__ __align__(16) char Bs[2][128 * 64];
  const int t = threadIdx.x;
  const int lane = t & 63;
  const int w = t >> 6;
  const int wr = w >> 1, wc = w & 1;
  const int lr = lane & 15, ksl = lane >> 4;

  const int srow = t >> 2, sch = t & 3;
  const float* pa = A + (size_t)(m0 + srow) * DMODEL + sch * 8;
  const float* pb = Bw + (size_t)(n0 + srow) * DMODEL + sch * 8;
  const int sd = srow * 64 + ((sch ^ (srow & 3)) * 16);

  // two register staging sets (static names -> no scratch, rule #20)
  f32x4 a0[4], b0[4], a1[4], b1[4];

  auto LOAD0 = [&]() {
    a0[0] = *(const f32x4*)pa;           a0[1] = *(const f32x4*)(pa + 4);
    a0[2] = *(const f32x4*)(pa + 65536); a0[3] = *(const f32x4*)(pa + 65540);
    b0[0] = *(const f32x4*)pb;           b0[1] = *(const f32x4*)(pb + 4);
    b0[2] = *(const f32x4*)(pb + 65536); b0[3] = *(const f32x4*)(pb + 65540);
    pa += 32; pb += 32;
  };
  auto LOAD1 = [&]() {
    a1[0] = *(const f32x4*)pa;           a1[1] = *(const f32x4*)(pa + 4);
    a1[2] = *(const f32x4*)(pa + 65536); a1[3] = *(const f32x4*)(pa + 65540);
    b1[0] = *(const f32x4*)pb;           b1[1] = *(const f32x4*)(pb + 4);
    b1[2] = *(const f32x4*)(pb + 65536); b1[3] = *(const f32x4*)(pb + 65540);
    pa += 32; pb += 32;
  };
  auto pack2 = [](f32x4 x, f32x4 y) {
    u16x8 r;
#pragma unroll
    for (int j = 0; j < 4; ++j) { r[j] = bfc(x[j]); r[4 + j] = bfc(y[j]); }
    return r;
  };
  auto STORE0 = [&](int buf) {
    char* ab = &As[buf][0];
    char* bb = &Bs[buf][0];
    *(u16x8*)(ab + sd) = pack2(a0[0], a0[1]);
    *(u16x8*)(ab + sd + 4096) = pack2(a0[2], a0[3]);
    *(u16x8*)(bb + sd) = pack2(b0[0], b0[1]);
    *(u16x8*)(bb + sd + 4096) = pack2(b0[2], b0[3]);
  };
  auto STORE1 = [&](int buf) {
    char* ab = &As[buf][0];
    char* bb = &Bs[buf][0];
    *(u16x8*)(ab + sd) = pack2(a1[0], a1[1]);
    *(u16x8*)(ab + sd + 4096) = pack2(a1[2], a1[3]);
    *(u16x8*)(bb + sd) = pack2(b1[0], b1[1]);
    *(u16x8*)(bb + sd + 4096) = pack2(b1[2], b1[3]);
  };

  f32x4 acc[4][4];
#pragma unroll
  for (int m = 0; m < 4; ++m)
#pragma unroll
    for (int n = 0; n < 4; ++n) acc[m][n] = (f32x4){0.f, 0.f, 0.f, 0.f};

  // prologue: tile0 -> LDS buf0; tile1 -> set0; tile2 -> set1 (in flight)
  LOAD0();
  STORE0(0);
  LOAD0();
  LOAD1();
  __syncthreads();

  const int co = (ksl ^ (lr & 3)) * 16;

  auto MFMA = [&](int cur) {
    const char* Ab = &As[cur][0];
    const char* Bb = &Bs[cur][0];
    bf16x8 af[4], bfv[4];
#pragma unroll
    for (int m = 0; m < 4; ++m)
      af[m] = *(const bf16x8*)(Ab + (wr * 64 + m * 16 + lr) * 64 + co);
#pragma unroll
    for (int n = 0; n < 4; ++n)
      bfv[n] = *(const bf16x8*)(Bb + (wc * 64 + n * 16 + lr) * 64 + co);
    __builtin_amdgcn_s_setprio(1);
#pragma unroll
    for (int m = 0; m < 4; ++m)
#pragma unroll
      for (int n = 0; n < 4; ++n)
        acc[m][n] = __builtin_amdgcn_mfma_f32_16x16x32_bf16(af[m], bfv[n], acc[m][n], 0, 0, 0);
    __builtin_amdgcn_s_setprio(0);
  };

  int cur = 0;
#pragma unroll 1
  for (int kt2 = 0; kt2 < 32; kt2 += 2) {
    // even iter kt = kt2: set0 holds tile kt+1
    MFMA(cur);
    if (kt2 < 31) STORE0(cur ^ 1);     // waits loads issued 2 iters ago
    if (kt2 + 3 <= 31) LOAD0();        // tile kt+3 in flight
    __syncthreads();
    cur ^= 1;
    // odd iter kt = kt2+1: set1 holds tile kt+1
    MFMA(cur);
    if (kt2 + 2 <= 31) STORE1(cur ^ 1);
    if (kt2 + 4 <= 31) LOAD1();
    __syncthreads();
    cur ^= 1;
  }

#pragma unroll
  for (int m = 0; m < 4; ++m) {
#pragma unroll
    for (int n = 0; n < 4; ++n) {
      int col = n0 + wc * 64 + n * 16 + lr;
#pragma unroll
      for (int r = 0; r < 4; ++r) {
        int row = m0 + wr * 64 + m * 16 + ksl * 4 + r;
        C[(size_t)row * DMODEL + col] = bfc(acc[m][n][r] * osc);
      }
    }
  }
}

// ---------------- output GEMM: C = A*Wo^T + resid, fp32 out, 64x128, BK=32 ---
// (R12-proven, unchanged)
__global__ __launch_bounds__(256, 4)
void gemm_o_kernel(const uint16_t* __restrict__ Ac, const float* __restrict__ Bw,
                   float* __restrict__ Cf, const float* __restrict__ resid) {
  int orig = blockIdx.x;                 // 512 blocks, 64-chunk per XCD
  int lin = (orig & 7) * 64 + (orig >> 3);
  int m0 = (lin >> 3) * 64, n0 = (lin & 7) * 128;

  __shared__ __align__(16) char As[2][64 * 64];
  __shared__ __align__(16) char Bs[2][128 * 64];
  const int t = threadIdx.x;
  const int lane = t & 63;
  const int w = t >> 6;
  const int wr = w >> 1, wc = w & 1;
  const int lr = lane & 15, ksl = lane >> 4;

  const int srow = t >> 2, sch = t & 3;
  const uint16_t* pc = Ac + (size_t)(m0 + srow) * DMODEL + sch * 8;
  const float* pb = Bw + (size_t)(n0 + srow) * DMODEL + sch * 8;
  const int sd = srow * 64 + ((sch ^ (srow & 3)) * 16);

  u16x8 lc;
  f32x4 lb0, lb1, lb2, lb3;
  auto LOAD = [&]() {
    lc = *(const u16x8*)pc;
    lb0 = *(const f32x4*)pb;           lb1 = *(const f32x4*)(pb + 4);
    lb2 = *(const f32x4*)(pb + 65536); lb3 = *(const f32x4*)(pb + 65540);
  };
  auto pack2 = [](f32x4 x, f32x4 y) {
    u16x8 r;
#pragma unroll
    for (int j = 0; j < 4; ++j) { r[j] = bfc(x[j]); r[4 + j] = bfc(y[j]); }
    return r;
  };
  auto STORE = [&](int buf) {
    *(u16x8*)(&As[buf][0] + sd) = lc;
    char* bb = &Bs[buf][0];
    *(u16x8*)(bb + sd) = pack2(lb0, lb1);
    *(u16x8*)(bb + sd + 4096) = pack2(lb2, lb3);
  };

  f32x4 acc[2][4];
#pragma unroll
  for (int m = 0; m < 2; ++m)
#pragma unroll
    for (int n = 0; n < 4; ++n) acc[m][n] = (f32x4){0.f, 0.f, 0.f, 0.f};

  LOAD();
  STORE(0);
  __syncthreads();

  const int co = (ksl ^ (lr & 3)) * 16;

  int cur = 0;
#pragma unroll 1
  for (int kt = 0; kt < 32; ++kt) {
    if (kt < 31) { pc += 32; pb += 32; LOAD(); }
    const char* Ab = &As[cur][0];
    const char* Bb = &Bs[cur][0];
    bf16x8 af[2], bfv[4];
#pragma unroll
    for (int m = 0; m < 2; ++m)
      af[m] = *(const bf16x8*)(Ab + (wr * 32 + m * 16 + lr) * 64 + co);
#pragma unroll
    for (int n = 0; n < 4; ++n)
      bfv[n] = *(const bf16x8*)(Bb + (wc * 64 + n * 16 + lr) * 64 + co);
    __builtin_amdgcn_s_setprio(1);
#pragma unroll
    for (int m = 0; m < 2; ++m)
#pragma unroll
      for (int n = 0; n < 4; ++n)
        acc[m][n] = __builtin_amdgcn_mfma_f32_16x16x32_bf16(af[m], bfv[n], acc[m][n], 0, 0, 0);
    __builtin_amdgcn_s_setprio(0);
    if (kt < 31) STORE(cur ^ 1);
    __syncthreads();
    cur ^= 1;
  }

#pragma unroll
  for (int m = 0; m < 2; ++m) {
#pragma unroll
    for (int n = 0; n < 4; ++n) {
      int col = n0 + wc * 64 + n * 16 + lr;
#pragma unroll
      for (int r = 0; r < 4; ++r) {
        int row = m0 + wr * 32 + m * 16 + ksl * 4 + r;
        size_t idx = (size_t)row * DMODEL + col;
        Cf[idx] = acc[m][n][r] + resid[idx];
      }
    }
  }
}

// ---------------- MFMA flash attention (R10-proven, unchanged) ---------------
__global__ __launch_bounds__(256, 4)
void attn_mfma_kernel(const uint16_t* __restrict__ Pq, const uint16_t* __restrict__ Pk,
                      const uint16_t* __restrict__ Pv, uint16_t* __restrict__ Cc) {
  __shared__ __align__(16) uint16_t Ks[2][64 * 64];
  __shared__ __align__(16) uint16_t Vts[2][64 * 64];

  const int t = threadIdx.x;
  const int w = t >> 6;
  const int lane = t & 63;
  const int lr = lane & 15;
  const int ksl = lane >> 4;
  int orig = blockIdx.x;
  int lin = (orig & 7) * 128 + (orig >> 3);
  const int bh = lin >> 4, qt = lin & 15;
  const int b = bh >> 4, h = bh & 15;

  const uint16_t* Qb = Pq + (size_t)bh * 65536 + (size_t)qt * 4096;
  const uint16_t* Kb = Pk + (size_t)bh * 65536;
  const uint16_t* Vb = Pv + (size_t)bh * 65536;

  bf16x8 qf0, qf1;
  {
    const uint16_t* qrow = Qb + (size_t)(w * 16 + lr) * 64 + ksl * 8;
    qf0 = *(const bf16x8*)(qrow);
    qf1 = *(const bf16x8*)(qrow + 32);
  }

  f32x4 Oa[4];
#pragma unroll
  for (int n = 0; n < 4; ++n) Oa[n] = (f32x4){0.f, 0.f, 0.f, 0.f};
  f32x4 lsum4 = {0.f, 0.f, 0.f, 0.f};

  const int sw = (lr & 7) << 4;
  const int p2 = t & 31;
  const int c8 = t >> 5;

  int qko[4][2], pvo[4][4], wvo[8];
#pragma unroll
  for (int n = 0; n < 4; ++n) {
#pragma unroll
    for (int c = 0; c < 2; ++c) qko[n][c] = (n * 16 + lr) * 128 + ((c * 64 + ksl * 16) ^ sw);
#pragma unroll
    for (int nd = 0; nd < 4; ++nd) pvo[n][nd] = (nd * 16 + lr) * 128 + ((n * 32 + ksl * 8) ^ sw);
  }
#pragma unroll
  for (int i = 0; i < 8; ++i) {
    int d = c8 * 8 + i;
    wvo[i] = d * 128 + ((p2 * 4) ^ ((d & 7) << 4));
  }

  const int sr0 = t >> 3;
  const int sc0 = (((t & 7) * 16) ^ ((sr0 & 7) << 4)) >> 1;
  const uint16_t* srcK = Kb + (size_t)sr0 * 64 + sc0;
  const uint16_t* srcV = Vb + (size_t)(p2 * 2) * 64 + c8 * 8;
  const int kd0 = t * 16, kd1 = (256 + t) * 16;

  char* kb0 = (char*)&Ks[0][0];
  char* kb1 = (char*)&Ks[1][0];
  char* vb0 = (char*)&Vts[0][0];
  char* vb1 = (char*)&Vts[1][0];

  u16x8 va, vb2;
  auto stageK = [&](char* kbuf) {
    gld16(srcK, kbuf + kd0);
    gld16(srcK + 2048, kbuf + kd1);
  };
  auto loadV = [&]() {
    va = *(const u16x8*)srcV;
    vb2 = *(const u16x8*)(srcV + 64);
  };
  auto writeV = [&](char* vbuf) {
#pragma unroll
    for (int i = 0; i < 8; ++i) {
      uint32_t val = (uint32_t)va[i] | ((uint32_t)vb2[i] << 16);
      *(uint32_t*)(vbuf + wvo[i]) = val;
    }
  };

  stageK(kb0);
  loadV();
  writeV(vb0);
  __syncthreads();

  const char* kcur = kb0; char* knx = kb1;
  const char* vcur = vb0; char* vnx = vb1;

#pragma unroll 1
  for (int kt = 0; kt < 16; ++kt) {
    if (kt < 15) { srcK += 4096; stageK(knx); srcV += 4096; loadV(); }

    f32x4 S[4];
#pragma unroll
    for (int n = 0; n < 4; ++n) S[n] = (f32x4){0.f, 0.f, 0.f, 0.f};
    __builtin_amdgcn_s_setprio(1);
#pragma unroll
    for (int n = 0; n < 4; ++n) {
      bf16x8 kf0 = *(const bf16x8*)(kcur + qko[n][0]);
      bf16x8 kf1 = *(const bf16x8*)(kcur + qko[n][1]);
      S[n] = __builtin_amdgcn_mfma_f32_16x16x32_bf16(kf0, qf0, S[n], 0, 0, 0);
      S[n] = __builtin_amdgcn_mfma_f32_16x16x32_bf16(kf1, qf1, S[n], 0, 0, 0);
    }
    __builtin_amdgcn_s_setprio(0);

    f32x4 psum = {0.f, 0.f, 0.f, 0.f};
    f32x4 p4[4];
#pragma unroll
    for (int n = 0; n < 4; ++n) {
#pragma unroll
      for (int r = 0; r < 4; ++r) {
        float x = S[n][r];
        float e = __builtin_amdgcn_exp2f(x);
        p4[n][r] = (x == 0.f) ? 0.f : e;
      }
      psum += p4[n];
    }
    lsum4 += psum;

    __builtin_amdgcn_s_setprio(1);
#pragma unroll
    for (int n = 0; n < 4; ++n) {
      u32x2 pa32 = {pk32(p4[n][0], p4[n][1]), pk32(p4[n][2], p4[n][3])};
      s16x4 pa = __builtin_bit_cast(s16x4, pa32);
#pragma unroll
      for (int nd = 0; nd < 4; ++nd) {
        s16x4 vf = *(const s16x4*)(vcur + pvo[n][nd]);
        Oa[nd] = __builtin_amdgcn_mfma_f32_16x16x16bf16_1k(pa, vf, Oa[nd], 0, 0, 0);
      }
    }
    __builtin_amdgcn_s_setprio(0);

    if (kt < 15) writeV(vnx);
    __syncthreads();
    const char* tk = kcur; kcur = knx; knx = (char*)tk;
    const char* tv = vcur; vcur = vnx; vnx = (char*)tv;
  }

  float lrow = (lsum4[0] + lsum4[1]) + (lsum4[2] + lsum4[3]);
  lrow += __shfl_xor(lrow, 16);
  lrow += __shfl_xor(lrow, 32);
  f32x4 inv4;
#pragma unroll
  for (int r = 0; r < 4; ++r) inv4[r] = 1.f / __shfl(lrow, ksl * 4 + r);

  uint16_t* dst = Cc + (size_t)b * 1048576 + (size_t)(qt * 64 + w * 16) * 1024 + h * 64;
#pragma unroll
  for (int r = 0; r < 4; ++r) {
    int qq = ksl * 4 + r;
#pragma unroll
    for (int n = 0; n < 4; ++n) {
      dst[qq * 1024 + n * 16 + lr] = bfc(Oa[n][r] * inv4[r]);
    }
  }
}

// ---------------- host-side orchestration ------------------------------------
extern "C" void kernel_launch(void* const* d_in, const int* in_sizes, int n_in,
                              void* d_out, int out_size, void* d_ws, size_t ws_size,
                              hipStream_t stream) {
  const float* q  = (const float*)d_in[0];
  const float* k  = (const float*)d_in[1];
  const float* v  = (const float*)d_in[2];
  const float* Wq = (const float*)d_in[3];
  const float* Wk = (const float*)d_in[4];
  const float* Wv = (const float*)d_in[5];
  const float* Wo = (const float*)d_in[6];
  float* out = (float*)d_out;
  char* ws = (char*)d_ws;
  const size_t MB = 1u << 20;
  uint16_t* Pq = (uint16_t*)(ws + 0 * MB);
  uint16_t* Pk = (uint16_t*)(ws + 8 * MB);
  uint16_t* Pv = (uint16_t*)(ws + 16 * MB);
  uint16_t* Cc = (uint16_t*)(ws + 24 * MB);

  gemm_qkv_kernel<<<768, 256, 0, stream>>>(q, k, v, Wq, Wk, Wv, Pq, Pk, Pv);

  attn_mfma_kernel<<<1024, 256, 0, stream>>>(Pq, Pk, Pv, Cc);

  gemm_o_kernel<<<512, 256, 0, stream>>>(Cc, Wo, out, q);
}

// Round 15
// 99.111 us; speedup vs baseline: 1.2612x; 1.0390x over previous
//
#include <hip/hip_runtime.h>
#include <stdint.h>

typedef __bf16 bf16x8 __attribute__((ext_vector_type(8)));
typedef __bf16 bf16x2v __attribute__((ext_vector_type(2)));
typedef float f32x4 __attribute__((ext_vector_type(4)));
typedef uint16_t u16x8 __attribute__((ext_vector_type(8)));
typedef uint16_t u16x4 __attribute__((ext_vector_type(4)));
typedef uint32_t u32x2 __attribute__((ext_vector_type(2)));
typedef short s16x4 __attribute__((ext_vector_type(4)));

#define DMODEL 1024
#define K1SC 0.1803368801111244f  /* (1/8) * log2(e) */

__device__ __forceinline__ uint16_t bfc(float f) {
  __bf16 h = (__bf16)f;
  return __builtin_bit_cast(uint16_t, h);
}
__device__ __forceinline__ uint32_t pk32(float a, float b) {
  bf16x2v t = {(__bf16)a, (__bf16)b};
  return __builtin_bit_cast(uint32_t, t);
}
__device__ __forceinline__ void gld16(const void* src, void* dst) {
  __builtin_amdgcn_global_load_lds((const __attribute__((address_space(1))) void*)src,
                                   (__attribute__((address_space(3))) void*)dst, 16, 0, 0);
}

// ---------------- fp32 -> bf16 convert, weights ONLY (16MB read, tiny) -------
__global__ void cvt_w_kernel(const float* __restrict__ Wq, const float* __restrict__ Wk,
                             const float* __restrict__ Wv, const float* __restrict__ Wo,
                             uint16_t* __restrict__ Wqb, uint16_t* __restrict__ Wkb,
                             uint16_t* __restrict__ Wvb, uint16_t* __restrict__ Wob) {
  int bid = blockIdx.x;                 // 4096 blocks: 1024 per matrix
  int s = bid >> 10;
  const float* src = s == 0 ? Wq : (s == 1 ? Wk : (s == 2 ? Wv : Wo));
  uint16_t* dst = s == 0 ? Wqb : (s == 1 ? Wkb : (s == 2 ? Wvb : Wob));
  int i = (bid & 1023) * 256 + threadIdx.x;
  f32x4 x = ((const f32x4*)src)[i];
  u16x4 r;
#pragma unroll
  for (int j = 0; j < 4; ++j) r[j] = bfc(x[j]);
  ((u16x4*)dst)[i] = r;
}

// ---------------- fused QKV projection: batched GEMM, 128x128, BK=32 ---------
// A staged as RAW FP32 via gld16 (fire-and-forget, no vmcnt stall, no cvt
// kernel for q/k/v): 128B rows, full 3-bit XOR via pre-swizzled source ->
// conflict-FREE A reads (rs = lr&7, offsets loop-invariant). LDS->reg convert
// at fragment load (8 v_cvt/frag). W pre-converted bf16, R6-proven staging.
// LDS 48KB -> 3 blocks/CU (= grid cap). z==0 (Q) pre-scaled by K1SC.
__global__ __launch_bounds__(256, 2)
void gemm_qkv_kernel(const float* __restrict__ A0, const float* __restrict__ A1,
                     const float* __restrict__ A2, const uint16_t* __restrict__ W0,
                     const uint16_t* __restrict__ W1, const uint16_t* __restrict__ W2,
                     uint16_t* __restrict__ C0, uint16_t* __restrict__ C1,
                     uint16_t* __restrict__ C2) {
  int orig = blockIdx.x;                 // 768 blocks, 96-chunk per XCD
  int lin = (orig & 7) * 96 + (orig >> 3);
  int z = lin >> 8, rem = lin & 255;
  int m0 = (rem >> 3) * 128, n0 = (rem & 7) * 128;

  const float* A = z == 0 ? A0 : (z == 1 ? A1 : A2);
  const uint16_t* Bw = z == 0 ? W0 : (z == 1 ? W1 : W2);
  uint16_t* C = z == 0 ? C0 : (z == 1 ? C1 : C2);
  const float osc = (z == 0) ? K1SC : 1.0f;

  __shared__ __align__(16) char As[2][128 * 128];     // fp32 tile: 16KB/buf
  __shared__ __align__(16) uint16_t Bs[2][128 * 32];  // bf16 tile:  8KB/buf
  const int t = threadIdx.x;
  const int lane = t & 63;
  const int w = t >> 6;
  const int wr = w >> 1, wc = w & 1;
  const int lr = lane & 15, ksl = lane >> 4;

  auto stage = [&](int buf, int k0) {
    // A: 1024 16B-chunks (8 per 128B row), pre-swizzled source chunk ch^(row&7)
#pragma unroll
    for (int cc = 0; cc < 4; ++cc) {
      int idx = cc * 256 + t;
      int row = idx >> 3, ch = idx & 7;
      int sc = (ch ^ (row & 7)) * 4;    // float offset within 32-float row
      gld16(A + (size_t)(m0 + row) * DMODEL + k0 + sc, &As[buf][idx * 16]);
    }
    // B (bf16): R6-proven 2-bit chunk XOR
#pragma unroll
    for (int cc = 0; cc < 2; ++cc) {
      int idx = cc * 256 + t;
      int row = idx >> 2, ch = idx & 3;
      int so = ((ch * 16) ^ ((row & 3) << 4)) >> 1;
      gld16(Bw + (size_t)(n0 + row) * DMODEL + k0 + so, &Bs[buf][idx * 8]);
    }
  };

  f32x4 acc[4][4];
#pragma unroll
  for (int m = 0; m < 4; ++m)
#pragma unroll
    for (int n = 0; n < 4; ++n) acc[m][n] = (f32x4){0.f, 0.f, 0.f, 0.f};

  stage(0, 0);
  __syncthreads();

  const int rs = lr & 7;                          // A row-swizzle key (invariant)
  const int aoff0 = ((2 * ksl) ^ rs) * 16;        // A chunk offsets (invariant)
  const int aoff1 = ((2 * ksl + 1) ^ rs) * 16;
  const int co = (ksl ^ (lr & 3)) * 16;           // B read offset

  int cur = 0;
#pragma unroll 1
  for (int kt = 0; kt < 32; ++kt) {
    if (kt < 31) stage(cur ^ 1, (kt + 1) * 32);
    const char* Ab = &As[cur][0];
    const char* Bb = (const char*)&Bs[cur][0];
    bf16x8 af[4], bfv[4];
#pragma unroll
    for (int m = 0; m < 4; ++m) {
      const char* rp = Ab + (wr * 64 + m * 16 + lr) * 128;
      f32x4 lo = *(const f32x4*)(rp + aoff0);
      f32x4 hi = *(const f32x4*)(rp + aoff1);
      u16x8 u;
#pragma unroll
      for (int j = 0; j < 4; ++j) { u[j] = bfc(lo[j]); u[4 + j] = bfc(hi[j]); }
      af[m] = __builtin_bit_cast(bf16x8, u);
    }
#pragma unroll
    for (int n = 0; n < 4; ++n)
      bfv[n] = *(const bf16x8*)(Bb + (wc * 64 + n * 16 + lr) * 64 + co);
    __builtin_amdgcn_s_setprio(1);
#pragma unroll
    for (int m = 0; m < 4; ++m)
#pragma unroll
      for (int n = 0; n < 4; ++n)
        acc[m][n] = __builtin_amdgcn_mfma_f32_16x16x32_bf16(af[m], bfv[n], acc[m][n], 0, 0, 0);
    __builtin_amdgcn_s_setprio(0);
    __syncthreads();
    cur ^= 1;
  }

#pragma unroll
  for (int m = 0; m < 4; ++m) {
#pragma unroll
    for (int n = 0; n < 4; ++n) {
      int col = n0 + wc * 64 + n * 16 + lr;
#pragma unroll
      for (int r = 0; r < 4; ++r) {
        int row = m0 + wr * 64 + m * 16 + ksl * 4 + r;
        C[(size_t)row * DMODEL + col] = bfc(acc[m][n][r] * osc);
      }
    }
  }
}

// ---------------- output GEMM: C = A*Wo^T + resid, fp32 out, 64x128, BK=32 ---
// All-bf16 gld16 (R6/R11-proven). A = Cc bf16, B = Wo bf16 (pre-converted).
__global__ __launch_bounds__(256, 2)
void gemm_o_kernel(const uint16_t* __restrict__ A, const uint16_t* __restrict__ Bw,
                   float* __restrict__ Cf, const float* __restrict__ resid) {
  int orig = blockIdx.x;                 // 512 blocks, 64-chunk per XCD
  int lin = (orig & 7) * 64 + (orig >> 3);
  int m0 = (lin >> 3) * 64, n0 = (lin & 7) * 128;

  __shared__ __align__(16) uint16_t As[2][64 * 32];
  __shared__ __align__(16) uint16_t Bs[2][128 * 32];
  const int t = threadIdx.x;
  const int lane = t & 63;
  const int w = t >> 6;
  const int wr = w >> 1, wc = w & 1;
  const int lr = lane & 15, ksl = lane >> 4;
  const int sw2 = (lr & 3) << 4;

  f32x4 acc[2][4];
#pragma unroll
  for (int m = 0; m < 2; ++m)
#pragma unroll
    for (int n = 0; n < 4; ++n) acc[m][n] = (f32x4){0.f, 0.f, 0.f, 0.f};

  auto stage = [&](int buf, int k0) {
    {
      int row = t >> 2, ch = t & 3;
      int so = ((ch * 16) ^ ((row & 3) << 4)) >> 1;
      gld16(A + (size_t)(m0 + row) * DMODEL + k0 + so, &As[buf][t * 8]);
    }
#pragma unroll
    for (int cc = 0; cc < 2; ++cc) {
      int idx = cc * 256 + t;
      int row = idx >> 2, ch = idx & 3;
      int so = ((ch * 16) ^ ((row & 3) << 4)) >> 1;
      gld16(Bw + (size_t)(n0 + row) * DMODEL + k0 + so, &Bs[buf][idx * 8]);
    }
  };

  stage(0, 0);
  __syncthreads();

  int cur = 0;
#pragma unroll 1
  for (int kt = 0; kt < 32; ++kt) {
    if (kt < 31) stage(cur ^ 1, (kt + 1) * 32);
    const char* Ab = (const char*)&As[cur][0];
    const char* Bb = (const char*)&Bs[cur][0];
    const int co = (ksl * 16) ^ sw2;
    bf16x8 af[2], bfv[4];
#pragma unroll
    for (int m = 0; m < 2; ++m)
      af[m] = *(const bf16x8*)(Ab + (wr * 32 + m * 16 + lr) * 64 + co);
#pragma unroll
    for (int n = 0; n < 4; ++n)
      bfv[n] = *(const bf16x8*)(Bb + (wc * 64 + n * 16 + lr) * 64 + co);
    __builtin_amdgcn_s_setprio(1);
#pragma unroll
    for (int m = 0; m < 2; ++m)
#pragma unroll
      for (int n = 0; n < 4; ++n)
        acc[m][n] = __builtin_amdgcn_mfma_f32_16x16x32_bf16(af[m], bfv[n], acc[m][n], 0, 0, 0);
    __builtin_amdgcn_s_setprio(0);
    __syncthreads();
    cur ^= 1;
  }

#pragma unroll
  for (int m = 0; m < 2; ++m) {
#pragma unroll
    for (int n = 0; n < 4; ++n) {
      int col = n0 + wc * 64 + n * 16 + lr;
#pragma unroll
      for (int r = 0; r < 4; ++r) {
        int row = m0 + wr * 32 + m * 16 + ksl * 4 + r;
        size_t idx = (size_t)row * DMODEL + col;
        Cf[idx] = acc[m][n][r] + resid[idx];
      }
    }
  }
}

// ---------------- MFMA flash attention (R10-proven, unchanged) ---------------
__global__ __launch_bounds__(256, 4)
void attn_mfma_kernel(const uint16_t* __restrict__ Pq, const uint16_t* __restrict__ Pk,
                      const uint16_t* __restrict__ Pv, uint16_t* __restrict__ Cc) {
  __shared__ __align__(16) uint16_t Ks[2][64 * 64];
  __shared__ __align__(16) uint16_t Vts[2][64 * 64];

  const int t = threadIdx.x;
  const int w = t >> 6;
  const int lane = t & 63;
  const int lr = lane & 15;
  const int ksl = lane >> 4;
  int orig = blockIdx.x;
  int lin = (orig & 7) * 128 + (orig >> 3);
  const int bh = lin >> 4, qt = lin & 15;
  const int b = bh >> 4, h = bh & 15;

  const uint16_t* Qb = Pq + (size_t)bh * 65536 + (size_t)qt * 4096;
  const uint16_t* Kb = Pk + (size_t)bh * 65536;
  const uint16_t* Vb = Pv + (size_t)bh * 65536;

  bf16x8 qf0, qf1;
  {
    const uint16_t* qrow = Qb + (size_t)(w * 16 + lr) * 64 + ksl * 8;
    qf0 = *(const bf16x8*)(qrow);
    qf1 = *(const bf16x8*)(qrow + 32);
  }

  f32x4 Oa[4];
#pragma unroll
  for (int n = 0; n < 4; ++n) Oa[n] = (f32x4){0.f, 0.f, 0.f, 0.f};
  f32x4 lsum4 = {0.f, 0.f, 0.f, 0.f};

  const int sw = (lr & 7) << 4;
  const int p2 = t & 31;
  const int c8 = t >> 5;

  int qko[4][2], pvo[4][4], wvo[8];
#pragma unroll
  for (int n = 0; n < 4; ++n) {
#pragma unroll
    for (int c = 0; c < 2; ++c) qko[n][c] = (n * 16 + lr) * 128 + ((c * 64 + ksl * 16) ^ sw);
#pragma unroll
    for (int nd = 0; nd < 4; ++nd) pvo[n][nd] = (nd * 16 + lr) * 128 + ((n * 32 + ksl * 8) ^ sw);
  }
#pragma unroll
  for (int i = 0; i < 8; ++i) {
    int d = c8 * 8 + i;
    wvo[i] = d * 128 + ((p2 * 4) ^ ((d & 7) << 4));
  }

  const int sr0 = t >> 3;
  const int sc0 = (((t & 7) * 16) ^ ((sr0 & 7) << 4)) >> 1;
  const uint16_t* srcK = Kb + (size_t)sr0 * 64 + sc0;
  const uint16_t* srcV = Vb + (size_t)(p2 * 2) * 64 + c8 * 8;
  const int kd0 = t * 16, kd1 = (256 + t) * 16;

  char* kb0 = (char*)&Ks[0][0];
  char* kb1 = (char*)&Ks[1][0];
  char* vb0 = (char*)&Vts[0][0];
  char* vb1 = (char*)&Vts[1][0];

  u16x8 va, vb2;
  auto stageK = [&](char* kbuf) {
    gld16(srcK, kbuf + kd0);
    gld16(srcK + 2048, kbuf + kd1);
  };
  auto loadV = [&]() {
    va = *(const u16x8*)srcV;
    vb2 = *(const u16x8*)(srcV + 64);
  };
  auto writeV = [&](char* vbuf) {
#pragma unroll
    for (int i = 0; i < 8; ++i) {
      uint32_t val = (uint32_t)va[i] | ((uint32_t)vb2[i] << 16);
      *(uint32_t*)(vbuf + wvo[i]) = val;
    }
  };

  stageK(kb0);
  loadV();
  writeV(vb0);
  __syncthreads();

  const char* kcur = kb0; char* knx = kb1;
  const char* vcur = vb0; char* vnx = vb1;

#pragma unroll 1
  for (int kt = 0; kt < 16; ++kt) {
    if (kt < 15) { srcK += 4096; stageK(knx); srcV += 4096; loadV(); }

    f32x4 S[4];
#pragma unroll
    for (int n = 0; n < 4; ++n) S[n] = (f32x4){0.f, 0.f, 0.f, 0.f};
    __builtin_amdgcn_s_setprio(1);
#pragma unroll
    for (int n = 0; n < 4; ++n) {
      bf16x8 kf0 = *(const bf16x8*)(kcur + qko[n][0]);
      bf16x8 kf1 = *(const bf16x8*)(kcur + qko[n][1]);
      S[n] = __builtin_amdgcn_mfma_f32_16x16x32_bf16(kf0, qf0, S[n], 0, 0, 0);
      S[n] = __builtin_amdgcn_mfma_f32_16x16x32_bf16(kf1, qf1, S[n], 0, 0, 0);
    }
    __builtin_amdgcn_s_setprio(0);

    f32x4 psum = {0.f, 0.f, 0.f, 0.f};
    f32x4 p4[4];
#pragma unroll
    for (int n = 0; n < 4; ++n) {
#pragma unroll
      for (int r = 0; r < 4; ++r) {
        float x = S[n][r];
        float e = __builtin_amdgcn_exp2f(x);
        p4[n][r] = (x == 0.f) ? 0.f : e;
      }
      psum += p4[n];
    }
    lsum4 += psum;

    __builtin_amdgcn_s_setprio(1);
#pragma unroll
    for (int n = 0; n < 4; ++n) {
      u32x2 pa32 = {pk32(p4[n][0], p4[n][1]), pk32(p4[n][2], p4[n][3])};
      s16x4 pa = __builtin_bit_cast(s16x4, pa32);
#pragma unroll
      for (int nd = 0; nd < 4; ++nd) {
        s16x4 vf = *(const s16x4*)(vcur + pvo[n][nd]);
        Oa[nd] = __builtin_amdgcn_mfma_f32_16x16x16bf16_1k(pa, vf, Oa[nd], 0, 0, 0);
      }
    }
    __builtin_amdgcn_s_setprio(0);

    if (kt < 15) writeV(vnx);
    __syncthreads();
    const char* tk = kcur; kcur = knx; knx = (char*)tk;
    const char* tv = vcur; vcur = vnx; vnx = (char*)tv;
  }

  float lrow = (lsum4[0] + lsum4[1]) + (lsum4[2] + lsum4[3]);
  lrow += __shfl_xor(lrow, 16);
  lrow += __shfl_xor(lrow, 32);
  f32x4 inv4;
#pragma unroll
  for (int r = 0; r < 4; ++r) inv4[r] = 1.f / __shfl(lrow, ksl * 4 + r);

  uint16_t* dst = Cc + (size_t)b * 1048576 + (size_t)(qt * 64 + w * 16) * 1024 + h * 64;
#pragma unroll
  for (int r = 0; r < 4; ++r) {
    int qq = ksl * 4 + r;
#pragma unroll
    for (int n = 0; n < 4; ++n) {
      dst[qq * 1024 + n * 16 + lr] = bfc(Oa[n][r] * inv4[r]);
    }
  }
}

// ---------------- host-side orchestration ------------------------------------
extern "C" void kernel_launch(void* const* d_in, const int* in_sizes, int n_in,
                              void* d_out, int out_size, void* d_ws, size_t ws_size,
                              hipStream_t stream) {
  const float* q  = (const float*)d_in[0];
  const float* k  = (const float*)d_in[1];
  const float* v  = (const float*)d_in[2];
  const float* Wq = (const float*)d_in[3];
  const float* Wk = (const float*)d_in[4];
  const float* Wv = (const float*)d_in[5];
  const float* Wo = (const float*)d_in[6];
  float* out = (float*)d_out;
  char* ws = (char*)d_ws;
  const size_t MB = 1u << 20;
  uint16_t* Pq  = (uint16_t*)(ws + 0 * MB);
  uint16_t* Pk  = (uint16_t*)(ws + 8 * MB);
  uint16_t* Pv  = (uint16_t*)(ws + 16 * MB);
  uint16_t* Cc  = (uint16_t*)(ws + 24 * MB);
  uint16_t* Wqb = (uint16_t*)(ws + 32 * MB);
  uint16_t* Wkb = (uint16_t*)(ws + 34 * MB);
  uint16_t* Wvb = (uint16_t*)(ws + 36 * MB);
  uint16_t* Wob = (uint16_t*)(ws + 38 * MB);

  cvt_w_kernel<<<4096, 256, 0, stream>>>(Wq, Wk, Wv, Wo, Wqb, Wkb, Wvb, Wob);

  gemm_qkv_kernel<<<768, 256, 0, stream>>>(q, k, v, Wqb, Wkb, Wvb, Pq, Pk, Pv);

  attn_mfma_kernel<<<1024, 256, 0, stream>>>(Pq, Pk, Pv, Cc);

  gemm_o_kernel<<<512, 256, 0, stream>>>(Cc, Wob, out, q);
}